// Round 2
// baseline (3887.951 us; speedup 1.0000x reference)
//
#include <hip/hip_runtime.h>
#include <stdint.h>
#include <stddef.h>

// ---------------------------------------------------------------------------
// PCgraph: T=32 steps of
//   mu   = tanh(x) @ w^T     (only cols n>=784 of mu are ever used)
//   e    = (x - mu) * m      (e[:, :784] == 0)
//   g    = e @ w             (rows k<784 of w dead; cols n<784 of g dead)
//   x    = x - 0.1 * m * (e - (1-tanh(x)^2) * g)
// bf16 MFMA (16x16x32), fp32 accum. x state lives in d_out (fp32).
// Mask structure: nodes [0,784) are clamped; we round 784 down to 768 (12*64)
// for tile alignment and keep w rows/cols only in the live range.
// ws footprint: 55.1 MiB (round-1 failure was OOB ws writes at 72+ MiB
// corrupting the harness's pristine input copies).
// ---------------------------------------------------------------------------

#define N_DIM 4096
#define B_DIM 256
#define T_STEPS 32
#define LR_X 0.1f
#define N0 768                      // first live column (aligned down from 784)
#define N_LIVE 3328                 // 4096 - 768, = 52 * 64

#define BM 64
#define BN 64
#define BK 64

typedef unsigned short ushort_t;
using bf16x8 = __attribute__((ext_vector_type(8))) __bf16;
using f32x4  = __attribute__((ext_vector_type(4))) float;

__device__ __forceinline__ ushort_t f2bf(float f) {
    union { float f; unsigned int u; } v; v.f = f;
    unsigned int r = v.u + 0x7fffu + ((v.u >> 16) & 1u);   // RNE
    return (ushort_t)(r >> 16);
}

__device__ __forceinline__ void async_copy16(const ushort_t* g, ushort_t* l) {
    __builtin_amdgcn_global_load_lds(
        (__attribute__((address_space(1))) void*)(g),
        (__attribute__((address_space(3))) void*)(l),
        16, 0, 0);
}

// --- w fp32 -> w_b bf16 [3328 x 4096] (rows 768..4095 of w)
//             + wt_b bf16 [3328 x 3328] (wt_b[n-768][k-768] = w[k][n]) --------
__global__ void convert_w(const float* __restrict__ w,
                          ushort_t* __restrict__ wb,
                          ushort_t* __restrict__ wtb) {
    __shared__ float tile[32][33];
    const int tx  = threadIdx.x & 31;
    const int ty  = threadIdx.x >> 5;            // 0..7
    const int bx  = blockIdx.x;                  // col tile over [0,4096)
    const int by  = blockIdx.y;                  // row tile over [768,4096)
#pragma unroll
    for (int rr = 0; rr < 32; rr += 8) {
        int rloc = by * 32 + rr + ty;            // row in w_b
        int c    = bx * 32 + tx;
        float v = w[(size_t)(N0 + rloc) * N_DIM + c];
        wb[(size_t)rloc * N_DIM + c] = f2bf(v);
        tile[rr + ty][tx] = v;
    }
    __syncthreads();
    if (bx >= N0 / 32) {                         // cols >= 768 also go to wt_b
#pragma unroll
        for (int rr = 0; rr < 32; rr += 8) {
            int r = bx * 32 - N0 + rr + ty;      // wt row = c_w - 768
            int c = by * 32 + tx;                // wt col = r_w - 768
            wtb[(size_t)r * N_LIVE + c] = f2bf(tile[tx][rr + ty]);
        }
    }
}

// --- x init: copy x into d_out, t = tanh(x) in bf16 -------------------------
__global__ void init_x(const float* __restrict__ xin,
                       float* __restrict__ xout,
                       ushort_t* __restrict__ tb) {
    int i = blockIdx.x * 256 + threadIdx.x;
    float v = xin[i];
    xout[i] = v;
    tb[i]   = f2bf(tanhf(v));
}

// --- fused GEMM + epilogue --------------------------------------------------
// C[m][n] = sum_k A[m][k] * B[nloc][kloc],  n = 768 + nloc, kloc = k - KSTART
// A: [256][4096] bf16 (k absolute). B: [3328][BSTR] bf16.
// PHASE 1: C = mu;  e = (x - mu)*mask  -> e_f32, e_bf16
// PHASE 2: C = g;   x -= LR*mask*(e - (1-tanh(x)^2)*g); t = tanh(x_new) bf16
template <int PHASE, int BSTR, int KSTART, int NKT>
__global__ __launch_bounds__(256) void gemm_step(
    const ushort_t* __restrict__ Amat,
    const ushort_t* __restrict__ Bmat,
    const float* xbuf,                 // no restrict: aliases xout in PHASE 2
    float* xout,
    const float* __restrict__ ef32_in,
    float* __restrict__ ef32_out,
    ushort_t* __restrict__ ebf16,
    ushort_t* __restrict__ tbf16,
    const int* __restrict__ mask) {
    // Fragment-order LDS: sub-tile s (msub = s>>1, ksub = s&1) occupies
    // 512 elements; staging lane L writes exactly the 16B that compute-lane L
    // reads -> all ds_read_b128 are lane-consecutive (conflict-free).
    __shared__ __align__(16) ushort_t As[2][BM * BK];
    __shared__ __align__(16) ushort_t Bs[2][BN * BK];

    const int tid    = threadIdx.x;
    const int lane   = tid & 63;
    const int wid    = tid >> 6;       // 0..3
    const int wave_m = wid >> 1;       // 0..1
    const int wave_n = wid & 1;        // 0..1
    const int n0loc = blockIdx.x * BN; // local col in live range
    const int m0    = blockIdx.y * BM;

    const int l15  = lane & 15;
    const int quad = lane >> 4;        // 0..3

    auto stage = [&](int buf, int kt) {
        const int k0 = KSTART + kt * BK;
#pragma unroll
        for (int u = 0; u < 2; ++u) {
            const int s    = wid * 2 + u;          // sub-tile id 0..7
            const int row  = (s >> 1) * 16 + l15;  // m (or n) within tile
            const int kk   = (s & 1) * 32 + (quad << 3);
            async_copy16(Amat + (size_t)(m0 + row) * N_DIM + k0 + kk,
                         &As[buf][s * 512 + lane * 8]);
            async_copy16(Bmat + (size_t)(n0loc + row) * BSTR + (k0 - KSTART) + kk,
                         &Bs[buf][s * 512 + lane * 8]);
        }
    };

    f32x4 acc[2][2] = {};

    auto compute = [&](int buf) {
#pragma unroll
        for (int ks = 0; ks < 2; ++ks) {
            bf16x8 a[2], b[2];
#pragma unroll
            for (int i = 0; i < 2; ++i) {
                const int asub = (wave_m * 2 + i) * 2 + ks;
                const int bsub = (wave_n * 2 + i) * 2 + ks;
                a[i] = *(const bf16x8*)(&As[buf][asub * 512 + lane * 8]);
                b[i] = *(const bf16x8*)(&Bs[buf][bsub * 512 + lane * 8]);
            }
#pragma unroll
            for (int i = 0; i < 2; ++i)
#pragma unroll
                for (int j = 0; j < 2; ++j)
                    acc[i][j] = __builtin_amdgcn_mfma_f32_16x16x32_bf16(
                        a[i], b[j], acc[i][j], 0, 0, 0);
        }
    };

    stage(0, 0);
    __syncthreads();
    for (int kt = 0; kt < NKT; ++kt) {
        if (kt + 1 < NKT) stage((kt + 1) & 1, kt + 1);
        compute(kt & 1);
        __syncthreads();   // drains prefetch vmcnt + protects LDS reuse
    }

    // Epilogue. C/D layout (verified m89/m91): col = lane&15, row = quad*4+reg
#pragma unroll
    for (int j = 0; j < 2; ++j) {
        const int n = N0 + n0loc + wave_n * 32 + j * 16 + l15;
        const float mval = (float)mask[n];
#pragma unroll
        for (int i = 0; i < 2; ++i) {
#pragma unroll
            for (int r = 0; r < 4; ++r) {
                const int m = m0 + wave_m * 32 + i * 16 + quad * 4 + r;
                const size_t idx = (size_t)m * N_DIM + n;
                const float v = acc[i][j][r];
                if (PHASE == 1) {
                    float e = (xbuf[idx] - v) * mval;
                    ef32_out[idx] = e;
                    ebf16[idx]    = f2bf(e);
                } else {
                    float xv   = xbuf[idx];
                    float th   = tanhf(xv);
                    float dEdx = ef32_in[idx] - (1.0f - th * th) * v;
                    float xn   = xv - LR_X * mval * dEdx;
                    xout[idx]  = xn;
                    tbf16[idx] = f2bf(tanhf(xn));
                }
            }
        }
    }
}

extern "C" void kernel_launch(void* const* d_in, const int* in_sizes, int n_in,
                              void* d_out, int out_size, void* d_ws, size_t ws_size,
                              hipStream_t stream) {
    const float* x_in  = (const float*)d_in[0];
    const float* w_in  = (const float*)d_in[1];
    const int*   mask  = (const int*)d_in[2];
    float*       xbuf  = (float*)d_out;          // state lives in d_out

    uint8_t* ws = (uint8_t*)d_ws;
    // ws layout (55.1 MiB total):
    ushort_t* w_b  = (ushort_t*)(ws);                    // 3328x4096 bf16 = 26 MiB
    ushort_t* wt_b = (ushort_t*)(ws + 27262976);         // 3328x3328 bf16 = 21.1 MiB
    ushort_t* t_b  = (ushort_t*)(ws + 49414144);         // 256x4096 bf16 = 2 MiB
    ushort_t* e_b  = (ushort_t*)(ws + 51511296);         // 256x4096 bf16 = 2 MiB
    float*    e_f  = (float*)   (ws + 53608448);         // 256x4096 f32  = 4 MiB
    // end @ 57802752 bytes

    convert_w<<<dim3(N_DIM / 32, N_LIVE / 32), 256, 0, stream>>>(w_in, w_b, wt_b);
    init_x<<<dim3((B_DIM * N_DIM) / 256), 256, 0, stream>>>(x_in, xbuf, t_b);

    for (int t = 0; t < T_STEPS; ++t) {
        // GEMM1: mu over live cols; A = tanh(x) [k: 0..4096), B = w_b
        gemm_step<1, N_DIM, 0, N_DIM / BK>
            <<<dim3(N_LIVE / BN, B_DIM / BM), 256, 0, stream>>>(
            t_b, w_b, xbuf, nullptr, nullptr, e_f, e_b, nullptr, mask);
        // GEMM2: g over live cols; A = e [k: 768..4096), B = wt_b
        gemm_step<2, N_LIVE, N0, N_LIVE / BK>
            <<<dim3(N_LIVE / BN, B_DIM / BM), 256, 0, stream>>>(
            e_b, wt_b, xbuf, xbuf, e_f, nullptr, nullptr, t_b, mask);
    }
}

// Round 3
// 3847.150 us; speedup vs baseline: 1.0106x; 1.0106x over previous
//
#include <hip/hip_runtime.h>
#include <stdint.h>
#include <stddef.h>

// ---------------------------------------------------------------------------
// PCgraph: T=32 steps of
//   mu   = tanh(x) @ w^T     (only cols n>=784 of mu are ever used)
//   e    = (x - mu) * m      (e[:, :784] == 0)
//   g    = e @ w             (rows k<784 of w dead; cols n<784 of g dead)
//   x    = x - 0.1 * m * (e - (1-tanh(x)^2) * g)
// bf16 MFMA (16x16x32), fp32 accum. x state lives in d_out (fp32).
// Round 3: 3-stage software-pipelined K-loop with per-wave fine-grained
// s_waitcnt vmcnt(4) + raw s_barrier (never vmcnt(0) mid-loop). Round-2
// profile showed 64 full-latency stalls per dispatch (__syncthreads drains
// the prefetch queue): MfmaUtil 4%, 63 us/dispatch, all pipes idle.
// ws footprint: 55.1 MiB (round-1 failure was OOB ws writes).
// ---------------------------------------------------------------------------

#define N_DIM 4096
#define B_DIM 256
#define T_STEPS 32
#define LR_X 0.1f
#define N0 768                      // first live column (aligned down from 784)
#define N_LIVE 3328                 // 4096 - 768, = 52 * 64

#define BM 64
#define BN 64
#define BK 64

typedef unsigned short ushort_t;
using bf16x8 = __attribute__((ext_vector_type(8))) __bf16;
using f32x4  = __attribute__((ext_vector_type(4))) float;

__device__ __forceinline__ ushort_t f2bf(float f) {
    union { float f; unsigned int u; } v; v.f = f;
    unsigned int r = v.u + 0x7fffu + ((v.u >> 16) & 1u);   // RNE
    return (ushort_t)(r >> 16);
}

__device__ __forceinline__ void async_copy16(const ushort_t* g, ushort_t* l) {
    __builtin_amdgcn_global_load_lds(
        (__attribute__((address_space(1))) void*)(g),
        (__attribute__((address_space(3))) void*)(l),
        16, 0, 0);
}

// s_waitcnt with vmcnt(N), lgkmcnt/expcnt unconstrained (gfx9 encoding:
// vmcnt[3:0] | expcnt<<4 | lgkmcnt<<8; vmcnt hi bits unused for N<16)
#define WAITCNT_VM(N) __builtin_amdgcn_s_waitcnt(0x0F70 | (N))

// --- w fp32 -> w_b bf16 [3328 x 4096] (rows 768..4095 of w)
//             + wt_b bf16 [3328 x 3328] (wt_b[n-768][k-768] = w[k][n]) --------
__global__ void convert_w(const float* __restrict__ w,
                          ushort_t* __restrict__ wb,
                          ushort_t* __restrict__ wtb) {
    __shared__ float tile[32][33];
    const int tx  = threadIdx.x & 31;
    const int ty  = threadIdx.x >> 5;            // 0..7
    const int bx  = blockIdx.x;                  // col tile over [0,4096)
    const int by  = blockIdx.y;                  // row tile over [768,4096)
#pragma unroll
    for (int rr = 0; rr < 32; rr += 8) {
        int rloc = by * 32 + rr + ty;            // row in w_b
        int c    = bx * 32 + tx;
        float v = w[(size_t)(N0 + rloc) * N_DIM + c];
        wb[(size_t)rloc * N_DIM + c] = f2bf(v);
        tile[rr + ty][tx] = v;
    }
    __syncthreads();
    if (bx >= N0 / 32) {                         // cols >= 768 also go to wt_b
#pragma unroll
        for (int rr = 0; rr < 32; rr += 8) {
            int r = bx * 32 - N0 + rr + ty;      // wt row = c_w - 768
            int c = by * 32 + tx;                // wt col = r_w - 768
            wtb[(size_t)r * N_LIVE + c] = f2bf(tile[tx][rr + ty]);
        }
    }
}

// --- x init: copy x into d_out, t = tanh(x) in bf16 -------------------------
__global__ void init_x(const float* __restrict__ xin,
                       float* __restrict__ xout,
                       ushort_t* __restrict__ tb) {
    int i = blockIdx.x * 256 + threadIdx.x;
    float v = xin[i];
    xout[i] = v;
    tb[i]   = f2bf(tanhf(v));
}

// --- fused GEMM + epilogue --------------------------------------------------
// C[m][n] = sum_k A[m][k] * B[nloc][kloc],  n = 768 + nloc, kloc = k - KSTART
// A: [256][4096] bf16 (k absolute). B: [3328][BSTR] bf16.
// PHASE 1: C = mu;  e = (x - mu)*mask  -> e_f32, e_bf16
// PHASE 2: C = g;   x -= LR*mask*(e - (1-tanh(x)^2)*g); t = tanh(x_new) bf16
template <int PHASE, int BSTR, int KSTART, int NKT>
__global__ __launch_bounds__(256) void gemm_step(
    const ushort_t* __restrict__ Amat,
    const ushort_t* __restrict__ Bmat,
    const float* xbuf,                 // no restrict: aliases xout in PHASE 2
    float* xout,
    const float* __restrict__ ef32_in,
    float* __restrict__ ef32_out,
    ushort_t* __restrict__ ebf16,
    ushort_t* __restrict__ tbf16,
    const int* __restrict__ mask) {
    // Fragment-order LDS: sub-tile s (msub = s>>1, ksub = s&1) occupies
    // 512 elements; staging lane L writes exactly the 16B that compute-lane L
    // reads -> all ds_read_b128 are lane-consecutive (conflict-free).
    // 3 pipeline stages: at iter k, chunks {k,k+1} are in flight; wave waits
    // vmcnt(4) (its own 4 chunk-k loads done), barriers, then stages k+2 into
    // buf (k+2)%3 == (k-1)%3, which every wave finished reading pre-barrier.
    __shared__ __align__(16) ushort_t As[3][BM * BK];
    __shared__ __align__(16) ushort_t Bs[3][BN * BK];

    const int tid    = threadIdx.x;
    const int lane   = tid & 63;
    const int wid    = tid >> 6;       // 0..3
    const int wave_m = wid >> 1;       // 0..1
    const int wave_n = wid & 1;        // 0..1
    const int n0loc = blockIdx.x * BN; // local col in live range
    const int m0    = blockIdx.y * BM;

    const int l15  = lane & 15;
    const int quad = lane >> 4;        // 0..3

    auto stage = [&](int buf, int kt) {
        const int k0 = KSTART + kt * BK;
#pragma unroll
        for (int u = 0; u < 2; ++u) {
            const int s    = wid * 2 + u;          // sub-tile id 0..7
            const int row  = (s >> 1) * 16 + l15;  // m (or n) within tile
            const int kk   = (s & 1) * 32 + (quad << 3);
            async_copy16(Amat + (size_t)(m0 + row) * N_DIM + k0 + kk,
                         &As[buf][s * 512 + lane * 8]);
            async_copy16(Bmat + (size_t)(n0loc + row) * BSTR + (k0 - KSTART) + kk,
                         &Bs[buf][s * 512 + lane * 8]);
        }
    };

    f32x4 acc[2][2] = {};

    auto compute = [&](int buf) {
#pragma unroll
        for (int ks = 0; ks < 2; ++ks) {
            bf16x8 a[2], b[2];
#pragma unroll
            for (int i = 0; i < 2; ++i) {
                const int asub = (wave_m * 2 + i) * 2 + ks;
                const int bsub = (wave_n * 2 + i) * 2 + ks;
                a[i] = *(const bf16x8*)(&As[buf][asub * 512 + lane * 8]);
                b[i] = *(const bf16x8*)(&Bs[buf][bsub * 512 + lane * 8]);
            }
#pragma unroll
            for (int i = 0; i < 2; ++i)
#pragma unroll
                for (int j = 0; j < 2; ++j)
                    acc[i][j] = __builtin_amdgcn_mfma_f32_16x16x32_bf16(
                        a[i], b[j], acc[i][j], 0, 0, 0);
        }
    };

    stage(0, 0);
    stage(1, 1);
    for (int kt = 0; kt < NKT; ++kt) {
        // own chunk-kt loads (4) done; leave chunk kt+1 (4) in flight
        if (kt + 1 < NKT) WAITCNT_VM(4); else WAITCNT_VM(0);
        __builtin_amdgcn_s_barrier();   // all waves' chunk-kt loads published
        if (kt + 2 < NKT) stage((kt + 2) % 3, kt + 2);
        compute(kt % 3);
    }

    // Epilogue. C/D layout (verified m89/m91): col = lane&15, row = quad*4+reg
#pragma unroll
    for (int j = 0; j < 2; ++j) {
        const int n = N0 + n0loc + wave_n * 32 + j * 16 + l15;
        const float mval = (float)mask[n];
#pragma unroll
        for (int i = 0; i < 2; ++i) {
#pragma unroll
            for (int r = 0; r < 4; ++r) {
                const int m = m0 + wave_m * 32 + i * 16 + quad * 4 + r;
                const size_t idx = (size_t)m * N_DIM + n;
                const float v = acc[i][j][r];
                if (PHASE == 1) {
                    float e = (xbuf[idx] - v) * mval;
                    ef32_out[idx] = e;
                    ebf16[idx]    = f2bf(e);
                } else {
                    float xv   = xbuf[idx];
                    float th   = tanhf(xv);
                    float dEdx = ef32_in[idx] - (1.0f - th * th) * v;
                    float xn   = xv - LR_X * mval * dEdx;
                    xout[idx]  = xn;
                    tbf16[idx] = f2bf(tanhf(xn));
                }
            }
        }
    }
}

extern "C" void kernel_launch(void* const* d_in, const int* in_sizes, int n_in,
                              void* d_out, int out_size, void* d_ws, size_t ws_size,
                              hipStream_t stream) {
    const float* x_in  = (const float*)d_in[0];
    const float* w_in  = (const float*)d_in[1];
    const int*   mask  = (const int*)d_in[2];
    float*       xbuf  = (float*)d_out;          // state lives in d_out

    uint8_t* ws = (uint8_t*)d_ws;
    // ws layout (55.1 MiB total):
    ushort_t* w_b  = (ushort_t*)(ws);                    // 3328x4096 bf16 = 26 MiB
    ushort_t* wt_b = (ushort_t*)(ws + 27262976);         // 3328x3328 bf16 = 21.1 MiB
    ushort_t* t_b  = (ushort_t*)(ws + 49414144);         // 256x4096 bf16 = 2 MiB
    ushort_t* e_b  = (ushort_t*)(ws + 51511296);         // 256x4096 bf16 = 2 MiB
    float*    e_f  = (float*)   (ws + 53608448);         // 256x4096 f32  = 4 MiB
    // end @ 57802752 bytes

    convert_w<<<dim3(N_DIM / 32, N_LIVE / 32), 256, 0, stream>>>(w_in, w_b, wt_b);
    init_x<<<dim3((B_DIM * N_DIM) / 256), 256, 0, stream>>>(x_in, xbuf, t_b);

    for (int t = 0; t < T_STEPS; ++t) {
        // GEMM1: mu over live cols; A = tanh(x) [k: 0..4096), B = w_b
        gemm_step<1, N_DIM, 0, N_DIM / BK>
            <<<dim3(N_LIVE / BN, B_DIM / BM), 256, 0, stream>>>(
            t_b, w_b, xbuf, nullptr, nullptr, e_f, e_b, nullptr, mask);
        // GEMM2: g over live cols; A = e [k: 768..4096), B = wt_b
        gemm_step<2, N_LIVE, N0, N_LIVE / BK>
            <<<dim3(N_LIVE / BN, B_DIM / BM), 256, 0, stream>>>(
            e_b, wt_b, xbuf, xbuf, e_f, nullptr, nullptr, t_b, mask);
    }
}